// Round 6
// baseline (236.824 us; speedup 1.0000x reference)
//
#include <hip/hip_runtime.h>

#define T_TOK  16384
#define IN_F   1024
#define OUT_F  1024
#define NE     8

typedef __bf16 bf16;
typedef bf16  bf16x4 __attribute__((ext_vector_type(4)));
typedef bf16  bf16x8 __attribute__((ext_vector_type(8)));
typedef float f32x4  __attribute__((ext_vector_type(4)));

// ---------------------------------------------------------------------------
// Pass 1: fp32 -> bf16 convert of x and W into workspace + zero-fill out
// (surplus-tile atomic flushes in pass 3 need out pre-zeroed).
// ---------------------------------------------------------------------------
#define CVT_THREADS 256
#define NX_CHUNKS (T_TOK * IN_F / 4)
#define NW_CHUNKS (NE * OUT_F * IN_F / 4)
#define NO_CHUNKS (T_TOK * OUT_F / 4)
#define NCVT_CHUNKS (NX_CHUNKS + NW_CHUNKS)
#define NALL_CHUNKS (NCVT_CHUNKS + NO_CHUNKS)

__global__ __launch_bounds__(CVT_THREADS)
void cvt_and_zero(const float* __restrict__ x, const float* __restrict__ w,
                  bf16* __restrict__ xb, bf16* __restrict__ wb,
                  float* __restrict__ out)
{
    for (int i = blockIdx.x * CVT_THREADS + threadIdx.x; i < NALL_CHUNKS;
         i += gridDim.x * CVT_THREADS) {
        if (i < NCVT_CHUNKS) {
            const bool isx = (i < NX_CHUNKS);
            const int  j   = isx ? i : i - NX_CHUNKS;
            f32x4 v = isx ? ((const f32x4*)x)[j] : ((const f32x4*)w)[j];
            bf16x4 h;
            #pragma unroll
            for (int k = 0; k < 4; ++k) h[k] = (bf16)v[k];
            if (isx) ((bf16x4*)xb)[j] = h;
            else     ((bf16x4*)wb)[j] = h;
        } else {
            f32x4 z = {0.f, 0.f, 0.f, 0.f};
            ((f32x4*)out)[i - NCVT_CHUNKS] = z;
        }
    }
}

// ---------------------------------------------------------------------------
// Shared GEMM geometry. 256x256 tile, BK=64, 8 waves (2M x 4N), 2-phase dbuf.
// ---------------------------------------------------------------------------
#define BM 256
#define BN 256
#define BK 64
#define GTHREADS 512
#define NBLOCKS 256
#define KCH (IN_F / BK)      // 16 K-chunks per tile

__device__ __forceinline__ void gld_lds16(const bf16* g, bf16* l) {
    __builtin_amdgcn_global_load_lds(
        (const __attribute__((address_space(1))) void*)g,
        (__attribute__((address_space(3))) void*)l,
        16, 0, 0);
}

__device__ __forceinline__ void resolve_slot(const int* sl, int slot,
                                             int& e_sel, int& row0, int& rows)
{
    e_sel = -1; row0 = 0; rows = 0;
    int start = 0, acct = 0;
    #pragma unroll
    for (int e = 0; e < NE; ++e) {
        int len = sl[e];
        int nt  = (len + BM - 1) >> 8;
        if (e_sel < 0 && slot >= acct && slot < acct + nt) {
            e_sel = e;
            row0  = start + (slot - acct) * BM;
            int rm = start + len - row0;
            rows = rm < BM ? rm : BM;
        }
        acct  += nt;
        start += len;
    }
}

// ---------------------------------------------------------------------------
// Pass 2: MAIN kernel — r3-verbatim hot loop (plain for, compiler-chosen
// unroll), grid = 256 blocks, tile index = blockIdx.x. One full tile per
// block; plain stores. Nothing else co-compiled into this kernel's loop.
// ---------------------------------------------------------------------------
__global__ __launch_bounds__(GTHREADS)
void grouped_gemm_main(const bf16* __restrict__ xb,
                       const bf16* __restrict__ wb,
                       const int*  __restrict__ seg_lens,
                       float* __restrict__ out)
{
    __shared__ __align__(16) bf16 As[2][BM * BK];   // 2 x 32 KiB
    __shared__ __align__(16) bf16 Bs[2][BN * BK];   // 2 x 32 KiB

    const int tile = blockIdx.x;        // 0..255; L >= 256 always
    const int slot = tile >> 2;
    const int col0 = (tile & 3) << 8;

    int sl[NE];
    #pragma unroll
    for (int e = 0; e < NE; ++e) sl[e] = seg_lens[e];

    int e_sel, row0, rows;
    resolve_slot(sl, slot, e_sel, row0, rows);
    if (e_sel < 0) return;   // unreachable (L >= 256), uniform safety exit

    const int tid  = threadIdx.x;
    const int lane = tid & 63;
    const int wave = tid >> 6;
    const int wr   = wave >> 2;
    const int wc   = wave & 3;
    const int quad = lane >> 4;
    const int l16  = lane & 15;
    const int rq   = lane >> 3;
    const int ke   = (lane & 7) * 8;
    const int q0   = wave * 4;

    const bf16* wbase = wb + ((size_t)e_sel * OUT_F + (size_t)col0) * IN_F;

    const bf16* ga[4];
    const bf16* gb[4];
    #pragma unroll
    for (int i = 0; i < 4; ++i) {
        int q  = wave * 4 + i;
        int ra = row0 + q * 8 + rq;
        if (ra > T_TOK - 1) ra = T_TOK - 1;
        ga[i] = xb + (size_t)ra * IN_F + ke;
        gb[i] = wbase + (size_t)(q * 8 + rq) * IN_F + ke;
    }

    f32x4 acc[8][4] = {};

    // prologue: stage K-tile 0 into buffer 0
    #pragma unroll
    for (int i = 0; i < 4; ++i) {
        gld_lds16(ga[i], &As[0][(q0 + i) * 512]);
        gld_lds16(gb[i], &Bs[0][(q0 + i) * 512]);
    }
    __syncthreads();

    int cur = 0;
    for (int ks = 0; ks < KCH; ++ks) {           // r3-verbatim: no pragma
        const int kn = (ks + 1) * BK;
        if (kn < IN_F) {
            #pragma unroll
            for (int i = 0; i < 4; ++i) {
                gld_lds16(ga[i] + kn, &As[cur ^ 1][(q0 + i) * 512]);
                gld_lds16(gb[i] + kn, &Bs[cur ^ 1][(q0 + i) * 512]);
            }
        }

        #pragma unroll
        for (int kk = 0; kk < 2; ++kk) {
            bf16x8 af[8], bfr[4];
            #pragma unroll
            for (int t = 0; t < 8; ++t)
                af[t] = *(const bf16x8*)(
                    &As[cur][(wr * 128 + t * 16 + l16) * BK + kk * 32 + quad * 8]);
            #pragma unroll
            for (int v = 0; v < 4; ++v)
                bfr[v] = *(const bf16x8*)(
                    &Bs[cur][(wc * 64 + v * 16 + l16) * BK + kk * 32 + quad * 8]);
            #pragma unroll
            for (int t = 0; t < 8; ++t)
                #pragma unroll
                for (int v = 0; v < 4; ++v)
                    acc[t][v] = __builtin_amdgcn_mfma_f32_16x16x32_bf16(
                        af[t], bfr[v], acc[t][v], 0, 0, 0);
        }

        __syncthreads();
        cur ^= 1;
    }

    // epilogue: plain store (sole contributor of this tile)
    #pragma unroll
    for (int t = 0; t < 8; ++t) {
        #pragma unroll
        for (int r = 0; r < 4; ++r) {
            int row = wr * 128 + t * 16 + quad * 4 + r;
            if (row < rows) {
                size_t ob = (size_t)(row0 + row) * OUT_F + col0 + wc * 64;
                #pragma unroll
                for (int v = 0; v < 4; ++v)
                    out[ob + v * 16 + l16] = acc[t][v][r];
            }
        }
    }
}

// ---------------------------------------------------------------------------
// Pass 3: SURPLUS kernel — stream-K units for tiles [256, L), atomic flush
// onto pre-zeroed out. <=2 units per block; runs after main kernel.
// ---------------------------------------------------------------------------
__global__ __launch_bounds__(GTHREADS)
void grouped_gemm_surplus(const bf16* __restrict__ xb,
                          const bf16* __restrict__ wb,
                          const int*  __restrict__ seg_lens,
                          float* __restrict__ out)
{
    __shared__ __align__(16) bf16 As[2][BM * BK];
    __shared__ __align__(16) bf16 Bs[2][BN * BK];

    const int tid  = threadIdx.x;
    const int lane = tid & 63;
    const int wave = tid >> 6;
    const int wr   = wave >> 2;
    const int wc   = wave & 3;
    const int quad = lane >> 4;
    const int l16  = lane & 15;
    const int rq   = lane >> 3;
    const int ke   = (lane & 7) * 8;
    const int q0   = wave * 4;
    const int b    = blockIdx.x;

    int sl[NE];
    #pragma unroll
    for (int e = 0; e < NE; ++e) sl[e] = seg_lens[e];

    int n_slots = 0;
    #pragma unroll
    for (int e = 0; e < NE; ++e) n_slots += (sl[e] + BM - 1) >> 8;
    const int L = n_slots * (OUT_F / BN);

    const int Uleft = (L - NBLOCKS) * KCH;
    if (Uleft <= 0) return;

    const int base = Uleft >> 8;
    const int rem  = Uleft & 255;
    int u    = NBLOCKS * KCH + b * base + (b < rem ? b : rem);
    int uend = u + base + (b < rem ? 1 : 0);

    while (u < uend) {
        const int tile = u >> 4;
        const int kc0  = u & (KCH - 1);
        int kc1 = kc0 + (uend - u);
        if (kc1 > KCH) kc1 = KCH;
        u += kc1 - kc0;

        const int slot = tile >> 2;
        const int col0 = (tile & 3) << 8;
        int e_sel, row0, rows;
        resolve_slot(sl, slot, e_sel, row0, rows);

        const bf16* wbase = wb + ((size_t)e_sel * OUT_F + (size_t)col0) * IN_F;

        const bf16* ga[4];
        const bf16* gb[4];
        #pragma unroll
        for (int i = 0; i < 4; ++i) {
            int q  = wave * 4 + i;
            int ra = row0 + q * 8 + rq;
            if (ra > T_TOK - 1) ra = T_TOK - 1;
            ga[i] = xb + (size_t)ra * IN_F + ke;
            gb[i] = wbase + (size_t)(q * 8 + rq) * IN_F + ke;
        }

        f32x4 acc[8][4] = {};

        {
            const int kb = kc0 * BK;
            #pragma unroll
            for (int i = 0; i < 4; ++i) {
                gld_lds16(ga[i] + kb, &As[0][(q0 + i) * 512]);
                gld_lds16(gb[i] + kb, &Bs[0][(q0 + i) * 512]);
            }
        }
        __syncthreads();

        int cur = 0;
        for (int ks = kc0; ks < kc1; ++ks) {
            const int kn = (ks + 1) * BK;
            if (ks + 1 < kc1) {
                #pragma unroll
                for (int i = 0; i < 4; ++i) {
                    gld_lds16(ga[i] + kn, &As[cur ^ 1][(q0 + i) * 512]);
                    gld_lds16(gb[i] + kn, &Bs[cur ^ 1][(q0 + i) * 512]);
                }
            }

            #pragma unroll
            for (int kk = 0; kk < 2; ++kk) {
                bf16x8 af[8], bfr[4];
                #pragma unroll
                for (int t = 0; t < 8; ++t)
                    af[t] = *(const bf16x8*)(
                        &As[cur][(wr * 128 + t * 16 + l16) * BK + kk * 32 + quad * 8]);
                #pragma unroll
                for (int v = 0; v < 4; ++v)
                    bfr[v] = *(const bf16x8*)(
                        &Bs[cur][(wc * 64 + v * 16 + l16) * BK + kk * 32 + quad * 8]);
                #pragma unroll
                for (int t = 0; t < 8; ++t)
                    #pragma unroll
                    for (int v = 0; v < 4; ++v)
                        acc[t][v] = __builtin_amdgcn_mfma_f32_16x16x32_bf16(
                            af[t], bfr[v], acc[t][v], 0, 0, 0);
            }

            __syncthreads();
            cur ^= 1;
        }

        // atomic flush (tile may have multiple contributing pieces)
        #pragma unroll
        for (int t = 0; t < 8; ++t) {
            #pragma unroll
            for (int r = 0; r < 4; ++r) {
                int row = wr * 128 + t * 16 + quad * 4 + r;
                if (row < rows) {
                    size_t ob = (size_t)(row0 + row) * OUT_F + col0 + wc * 64;
                    #pragma unroll
                    for (int v = 0; v < 4; ++v)
                        unsafeAtomicAdd(&out[ob + v * 16 + l16], acc[t][v][r]);
                }
            }
        }
    }
}

// ---------------------------------------------------------------------------
// Fallback (ws too small): round-0 kernel — fp32 loads, in-loop cvt.
// ---------------------------------------------------------------------------
#define FBM 128
#define FBK 32
#define FTHREADS 256
#define FROW_SLOTS 136

__global__ __launch_bounds__(FTHREADS)
void grouped_gemm_f32io_bf16(const float* __restrict__ x,
                             const float* __restrict__ wgt,
                             const int*  __restrict__ seg_lens,
                             float* __restrict__ out)
{
    __shared__ __align__(16) bf16 Asf[FBM * FBK];
    __shared__ __align__(16) bf16 Bsf[FBM * FBK];

    const int m    = blockIdx.y;
    const int col0 = blockIdx.x * FBM;

    int e_sel = -1, row0 = 0, rows = 0;
    {
        int start = 0, acct = 0;
        #pragma unroll
        for (int e = 0; e < NE; ++e) {
            int len = seg_lens[e];
            int nt  = (len + FBM - 1) >> 7;
            if (e_sel < 0 && m >= acct && m < acct + nt) {
                e_sel = e;
                row0  = start + (m - acct) * FBM;
                int rem = start + len - row0;
                rows = rem < FBM ? rem : FBM;
            }
            acct  += nt;
            start += len;
        }
    }
    if (e_sel < 0) return;

    const int tid  = threadIdx.x;
    const int lane = tid & 63;
    const int wave = tid >> 6;
    const int wm   = (wave >> 1) * 64;
    const int wn   = (wave & 1) * 64;
    const int quad = lane >> 4;
    const int l16  = lane & 15;

    const float* wbase = wgt + ((size_t)e_sel * OUT_F + (size_t)col0) * IN_F;

    f32x4 acc[4][4] = {};

    for (int k0 = 0; k0 < IN_F; k0 += FBK) {
        f32x4 a_st[4], b_st[4];
        #pragma unroll
        for (int t = 0; t < 4; ++t) {
            int c  = t * FTHREADS + tid;
            int rg = row0 + (c >> 3);
            if (rg > T_TOK - 1) rg = T_TOK - 1;
            a_st[t] = *(const f32x4*)(x + (size_t)rg * IN_F + k0 + (c & 7) * 4);
            b_st[t] = *(const f32x4*)(wbase + (size_t)(c >> 3) * IN_F + k0 + (c & 7) * 4);
        }

        __syncthreads();

        #pragma unroll
        for (int t = 0; t < 4; ++t) {
            int c = t * FTHREADS + tid;
            bf16x4 ha, hb;
            #pragma unroll
            for (int j = 0; j < 4; ++j) { ha[j] = (bf16)a_st[t][j]; hb[j] = (bf16)b_st[t][j]; }
            *(bf16x4*)(&Asf[(c >> 3) * FBK + (c & 7) * 4]) = ha;
            *(bf16x4*)(&Bsf[(c >> 3) * FBK + (c & 7) * 4]) = hb;
        }
        __syncthreads();

        bf16x8 af[4], bfr[4];
        #pragma unroll
        for (int t = 0; t < 4; ++t)
            af[t] = *(const bf16x8*)(&Asf[(wm + t * 16 + l16) * FBK + quad * 8]);
        #pragma unroll
        for (int v = 0; v < 4; ++v)
            bfr[v] = *(const bf16x8*)(&Bsf[(wn + v * 16 + l16) * FBK + quad * 8]);

        #pragma unroll
        for (int t = 0; t < 4; ++t)
            #pragma unroll
            for (int v = 0; v < 4; ++v)
                acc[t][v] = __builtin_amdgcn_mfma_f32_16x16x32_bf16(
                    af[t], bfr[v], acc[t][v], 0, 0, 0);
    }

    #pragma unroll
    for (int t = 0; t < 4; ++t) {
        #pragma unroll
        for (int r = 0; r < 4; ++r) {
            int row = wm + t * 16 + quad * 4 + r;
            if (row < rows) {
                size_t ob = (size_t)(row0 + row) * OUT_F + col0;
                #pragma unroll
                for (int v = 0; v < 4; ++v)
                    out[ob + wn + v * 16 + l16] = acc[t][v][r];
            }
        }
    }
}

extern "C" void kernel_launch(void* const* d_in, const int* in_sizes, int n_in,
                              void* d_out, int out_size, void* d_ws, size_t ws_size,
                              hipStream_t stream) {
    const float* x   = (const float*)d_in[0];
    const float* wgt = (const float*)d_in[1];
    const int*   seg = (const int*)d_in[2];
    float* out = (float*)d_out;

    const size_t xbytes = (size_t)T_TOK * IN_F * sizeof(bf16);       // 33.55 MB
    const size_t wbytes = (size_t)NE * OUT_F * IN_F * sizeof(bf16);  // 16.78 MB

    if (ws_size >= xbytes + wbytes) {
        bf16* xb = (bf16*)d_ws;
        bf16* wb = (bf16*)((char*)d_ws + xbytes);
        cvt_and_zero<<<dim3(2048, 1, 1), dim3(CVT_THREADS, 1, 1), 0, stream>>>(
            x, wgt, xb, wb, out);
        grouped_gemm_main<<<dim3(NBLOCKS, 1, 1), dim3(GTHREADS, 1, 1), 0, stream>>>(
            xb, wb, seg, out);
        grouped_gemm_surplus<<<dim3(NBLOCKS, 1, 1), dim3(GTHREADS, 1, 1), 0, stream>>>(
            xb, wb, seg, out);
    } else {
        grouped_gemm_f32io_bf16<<<dim3(OUT_F / FBM, FROW_SLOTS, 1),
                                  dim3(FTHREADS, 1, 1), 0, stream>>>(x, wgt, seg, out);
    }
}

// Round 7
// 214.992 us; speedup vs baseline: 1.1015x; 1.1015x over previous
//
#include <hip/hip_runtime.h>

#define T_TOK  16384
#define IN_F   1024
#define OUT_F  1024
#define NE     8

typedef __bf16 bf16;
typedef bf16  bf16x4 __attribute__((ext_vector_type(4)));
typedef bf16  bf16x8 __attribute__((ext_vector_type(8)));
typedef float f32x4  __attribute__((ext_vector_type(4)));

// ---------------------------------------------------------------------------
// Shared GEMM geometry. 256x256 tile, BK=64, 8 waves (2M x 4N), 2-phase dbuf.
// ---------------------------------------------------------------------------
#define BM 256
#define BN 256
#define BK 64
#define GTHREADS 512
#define NBLOCKS 256
#define KCH (IN_F / BK)      // 16 K-chunks per tile
#define SP_BLOCKS 112        // 28 surplus tiles x 4 K-slices (max)

// ---------------------------------------------------------------------------
// Pass 1: fp32 -> bf16 convert of x and W into workspace + zero-fill ONLY the
// surplus rows [R64, T_TOK) (rows of slots >= 64 — the only region receiving
// atomic flushes). <= 7 MB instead of 67 MB.
// ---------------------------------------------------------------------------
#define CVT_THREADS 256
#define NX_CHUNKS (T_TOK * IN_F / 4)
#define NW_CHUNKS (NE * OUT_F * IN_F / 4)
#define NCVT_CHUNKS (NX_CHUNKS + NW_CHUNKS)

__global__ __launch_bounds__(CVT_THREADS)
void cvt_and_zero(const float* __restrict__ x, const float* __restrict__ w,
                  bf16* __restrict__ xb, bf16* __restrict__ wb,
                  const int* __restrict__ seg_lens, float* __restrict__ out)
{
    // R64 = first row of slot 64 (slots tile [0,T_TOK) contiguously in order)
    int r64 = T_TOK;
    {
        int slots = 0, start = 0;
        #pragma unroll
        for (int e = 0; e < NE; ++e) {
            int len = seg_lens[e];
            int nt  = (len + BM - 1) >> 8;
            if (slots <= 64 && slots + nt > 64) {
                r64 = start + (64 - slots) * BM;
            }
            slots += nt;
            start += len;
        }
    }
    const int zero_chunks = (T_TOK - r64) * (OUT_F / 4);
    const int zbase       = r64 * (OUT_F / 4);
    const int tot         = NCVT_CHUNKS + zero_chunks;

    for (int i = blockIdx.x * CVT_THREADS + threadIdx.x; i < tot;
         i += gridDim.x * CVT_THREADS) {
        if (i < NCVT_CHUNKS) {
            const bool isx = (i < NX_CHUNKS);
            const int  j   = isx ? i : i - NX_CHUNKS;
            f32x4 v = isx ? ((const f32x4*)x)[j] : ((const f32x4*)w)[j];
            bf16x4 h;
            #pragma unroll
            for (int k = 0; k < 4; ++k) h[k] = (bf16)v[k];
            if (isx) ((bf16x4*)xb)[j] = h;
            else     ((bf16x4*)wb)[j] = h;
        } else {
            f32x4 z = {0.f, 0.f, 0.f, 0.f};
            ((f32x4*)out)[zbase + (i - NCVT_CHUNKS)] = z;
        }
    }
}

// ---------------------------------------------------------------------------
// Common helpers
// ---------------------------------------------------------------------------
__device__ __forceinline__ void gld_lds16(const bf16* g, bf16* l) {
    __builtin_amdgcn_global_load_lds(
        (const __attribute__((address_space(1))) void*)g,
        (__attribute__((address_space(3))) void*)l,
        16, 0, 0);
}

__device__ __forceinline__ void resolve_slot(const int* sl, int slot,
                                             int& e_sel, int& row0, int& rows)
{
    e_sel = -1; row0 = 0; rows = 0;
    int start = 0, acct = 0;
    #pragma unroll
    for (int e = 0; e < NE; ++e) {
        int len = sl[e];
        int nt  = (len + BM - 1) >> 8;
        if (e_sel < 0 && slot >= acct && slot < acct + nt) {
            e_sel = e;
            row0  = start + (slot - acct) * BM;
            int rm = start + len - row0;
            rows = rm < BM ? rm : BM;
        }
        acct  += nt;
        start += len;
    }
}

// ---------------------------------------------------------------------------
// Pass 2: MAIN kernel — UNCHANGED from r6 (measured 59.6 us, 3.7 us/chunk).
// Grid = 256 blocks, one full tile each, plain stores.
// ---------------------------------------------------------------------------
__global__ __launch_bounds__(GTHREADS)
void grouped_gemm_main(const bf16* __restrict__ xb,
                       const bf16* __restrict__ wb,
                       const int*  __restrict__ seg_lens,
                       float* __restrict__ out)
{
    __shared__ __align__(16) bf16 As[2][BM * BK];   // 2 x 32 KiB
    __shared__ __align__(16) bf16 Bs[2][BN * BK];   // 2 x 32 KiB

    const int tile = blockIdx.x;        // 0..255; L >= 256 always
    const int slot = tile >> 2;
    const int col0 = (tile & 3) << 8;

    int sl[NE];
    #pragma unroll
    for (int e = 0; e < NE; ++e) sl[e] = seg_lens[e];

    int e_sel, row0, rows;
    resolve_slot(sl, slot, e_sel, row0, rows);
    if (e_sel < 0) return;   // unreachable (L >= 256), uniform safety exit

    const int tid  = threadIdx.x;
    const int lane = tid & 63;
    const int wave = tid >> 6;
    const int wr   = wave >> 2;
    const int wc   = wave & 3;
    const int quad = lane >> 4;
    const int l16  = lane & 15;
    const int rq   = lane >> 3;
    const int ke   = (lane & 7) * 8;
    const int q0   = wave * 4;

    const bf16* wbase = wb + ((size_t)e_sel * OUT_F + (size_t)col0) * IN_F;

    const bf16* ga[4];
    const bf16* gb[4];
    #pragma unroll
    for (int i = 0; i < 4; ++i) {
        int q  = wave * 4 + i;
        int ra = row0 + q * 8 + rq;
        if (ra > T_TOK - 1) ra = T_TOK - 1;
        ga[i] = xb + (size_t)ra * IN_F + ke;
        gb[i] = wbase + (size_t)(q * 8 + rq) * IN_F + ke;
    }

    f32x4 acc[8][4] = {};

    // prologue: stage K-tile 0 into buffer 0
    #pragma unroll
    for (int i = 0; i < 4; ++i) {
        gld_lds16(ga[i], &As[0][(q0 + i) * 512]);
        gld_lds16(gb[i], &Bs[0][(q0 + i) * 512]);
    }
    __syncthreads();

    int cur = 0;
    for (int ks = 0; ks < KCH; ++ks) {           // compiler-chosen unroll
        const int kn = (ks + 1) * BK;
        if (kn < IN_F) {
            #pragma unroll
            for (int i = 0; i < 4; ++i) {
                gld_lds16(ga[i] + kn, &As[cur ^ 1][(q0 + i) * 512]);
                gld_lds16(gb[i] + kn, &Bs[cur ^ 1][(q0 + i) * 512]);
            }
        }

        #pragma unroll
        for (int kk = 0; kk < 2; ++kk) {
            bf16x8 af[8], bfr[4];
            #pragma unroll
            for (int t = 0; t < 8; ++t)
                af[t] = *(const bf16x8*)(
                    &As[cur][(wr * 128 + t * 16 + l16) * BK + kk * 32 + quad * 8]);
            #pragma unroll
            for (int v = 0; v < 4; ++v)
                bfr[v] = *(const bf16x8*)(
                    &Bs[cur][(wc * 64 + v * 16 + l16) * BK + kk * 32 + quad * 8]);
            #pragma unroll
            for (int t = 0; t < 8; ++t)
                #pragma unroll
                for (int v = 0; v < 4; ++v)
                    acc[t][v] = __builtin_amdgcn_mfma_f32_16x16x32_bf16(
                        af[t], bfr[v], acc[t][v], 0, 0, 0);
        }

        __syncthreads();
        cur ^= 1;
    }

    // epilogue: plain store (sole contributor of this tile)
    #pragma unroll
    for (int t = 0; t < 8; ++t) {
        #pragma unroll
        for (int r = 0; r < 4; ++r) {
            int row = wr * 128 + t * 16 + quad * 4 + r;
            if (row < rows) {
                size_t ob = (size_t)(row0 + row) * OUT_F + col0 + wc * 64;
                #pragma unroll
                for (int v = 0; v < 4; ++v)
                    out[ob + v * 16 + l16] = acc[t][v][r];
            }
        }
    }
}

// ---------------------------------------------------------------------------
// Pass 3: SURPLUS kernel — K-split-by-4. Each surplus tile (index >= 256)
// is computed by exactly 4 blocks (K-chunks 0-3 / 4-7 / 8-11 / 12-15).
// Static trip-count inner loop (no runtime-loop deopt; 'cur' = j&1 static).
// Flush = ONE atomic pass per block -> 112 x 256 KB = 29 MB atomic traffic
// (r6's <=2-unit pieces caused ~16x flush amplification, ~38 us).
// ---------------------------------------------------------------------------
__global__ __launch_bounds__(GTHREADS)
void grouped_gemm_surplus(const bf16* __restrict__ xb,
                          const bf16* __restrict__ wb,
                          const int*  __restrict__ seg_lens,
                          float* __restrict__ out)
{
    __shared__ __align__(16) bf16 As[2][BM * BK];
    __shared__ __align__(16) bf16 Bs[2][BN * BK];

    const int tile   = NBLOCKS + (blockIdx.x >> 2);
    const int kslice = blockIdx.x & 3;

    int sl[NE];
    #pragma unroll
    for (int e = 0; e < NE; ++e) sl[e] = seg_lens[e];

    int n_slots = 0;
    #pragma unroll
    for (int e = 0; e < NE; ++e) n_slots += (sl[e] + BM - 1) >> 8;
    const int L = n_slots * (OUT_F / BN);
    if (tile >= L) return;    // block-uniform exit before any barrier

    const int slot = tile >> 2;
    const int col0 = (tile & 3) << 8;
    int e_sel, row0, rows;
    resolve_slot(sl, slot, e_sel, row0, rows);

    const int tid  = threadIdx.x;
    const int lane = tid & 63;
    const int wave = tid >> 6;
    const int wr   = wave >> 2;
    const int wc   = wave & 3;
    const int quad = lane >> 4;
    const int l16  = lane & 15;
    const int rq   = lane >> 3;
    const int ke   = (lane & 7) * 8;
    const int q0   = wave * 4;

    const bf16* wbase = wb + ((size_t)e_sel * OUT_F + (size_t)col0) * IN_F;

    const bf16* ga[4];
    const bf16* gb[4];
    #pragma unroll
    for (int i = 0; i < 4; ++i) {
        int q  = wave * 4 + i;
        int ra = row0 + q * 8 + rq;
        if (ra > T_TOK - 1) ra = T_TOK - 1;
        ga[i] = xb + (size_t)ra * IN_F + ke;
        gb[i] = wbase + (size_t)(q * 8 + rq) * IN_F + ke;
    }

    f32x4 acc[8][4] = {};

    const int kb0 = kslice * 4 * BK;    // byte^H^H element base of chunk kc0

    // prologue: stage chunk kc0 into buffer 0
    #pragma unroll
    for (int i = 0; i < 4; ++i) {
        gld_lds16(ga[i] + kb0, &As[0][(q0 + i) * 512]);
        gld_lds16(gb[i] + kb0, &Bs[0][(q0 + i) * 512]);
    }
    __syncthreads();

    #pragma unroll
    for (int j = 0; j < 4; ++j) {       // static trip count: cur = j&1 static
        const int cur = j & 1;
        if (j < 3) {
            const int kn = kb0 + (j + 1) * BK;
            #pragma unroll
            for (int i = 0; i < 4; ++i) {
                gld_lds16(ga[i] + kn, &As[cur ^ 1][(q0 + i) * 512]);
                gld_lds16(gb[i] + kn, &Bs[cur ^ 1][(q0 + i) * 512]);
            }
        }

        #pragma unroll
        for (int kk = 0; kk < 2; ++kk) {
            bf16x8 af[8], bfr[4];
            #pragma unroll
            for (int t = 0; t < 8; ++t)
                af[t] = *(const bf16x8*)(
                    &As[cur][(wr * 128 + t * 16 + l16) * BK + kk * 32 + quad * 8]);
            #pragma unroll
            for (int v = 0; v < 4; ++v)
                bfr[v] = *(const bf16x8*)(
                    &Bs[cur][(wc * 64 + v * 16 + l16) * BK + kk * 32 + quad * 8]);
            #pragma unroll
            for (int t = 0; t < 8; ++t)
                #pragma unroll
                for (int v = 0; v < 4; ++v)
                    acc[t][v] = __builtin_amdgcn_mfma_f32_16x16x32_bf16(
                        af[t], bfr[v], acc[t][v], 0, 0, 0);
        }

        __syncthreads();
    }

    // single atomic flush (out pre-zeroed over surplus rows)
    #pragma unroll
    for (int t = 0; t < 8; ++t) {
        #pragma unroll
        for (int r = 0; r < 4; ++r) {
            int row = wr * 128 + t * 16 + quad * 4 + r;
            if (row < rows) {
                size_t ob = (size_t)(row0 + row) * OUT_F + col0 + wc * 64;
                #pragma unroll
                for (int v = 0; v < 4; ++v)
                    unsafeAtomicAdd(&out[ob + v * 16 + l16], acc[t][v][r]);
            }
        }
    }
}

// ---------------------------------------------------------------------------
// Fallback (ws too small): round-0 kernel — fp32 loads, in-loop cvt.
// ---------------------------------------------------------------------------
#define FBM 128
#define FBK 32
#define FTHREADS 256
#define FROW_SLOTS 136

__global__ __launch_bounds__(FTHREADS)
void grouped_gemm_f32io_bf16(const float* __restrict__ x,
                             const float* __restrict__ wgt,
                             const int*  __restrict__ seg_lens,
                             float* __restrict__ out)
{
    __shared__ __align__(16) bf16 Asf[FBM * FBK];
    __shared__ __align__(16) bf16 Bsf[FBM * FBK];

    const int m    = blockIdx.y;
    const int col0 = blockIdx.x * FBM;

    int e_sel = -1, row0 = 0, rows = 0;
    {
        int start = 0, acct = 0;
        #pragma unroll
        for (int e = 0; e < NE; ++e) {
            int len = seg_lens[e];
            int nt  = (len + FBM - 1) >> 7;
            if (e_sel < 0 && m >= acct && m < acct + nt) {
                e_sel = e;
                row0  = start + (m - acct) * FBM;
                int rem = start + len - row0;
                rows = rem < FBM ? rem : FBM;
            }
            acct  += nt;
            start += len;
        }
    }
    if (e_sel < 0) return;

    const int tid  = threadIdx.x;
    const int lane = tid & 63;
    const int wave = tid >> 6;
    const int wm   = (wave >> 1) * 64;
    const int wn   = (wave & 1) * 64;
    const int quad = lane >> 4;
    const int l16  = lane & 15;

    const float* wbase = wgt + ((size_t)e_sel * OUT_F + (size_t)col0) * IN_F;

    f32x4 acc[4][4] = {};

    for (int k0 = 0; k0 < IN_F; k0 += FBK) {
        f32x4 a_st[4], b_st[4];
        #pragma unroll
        for (int t = 0; t < 4; ++t) {
            int c  = t * FTHREADS + tid;
            int rg = row0 + (c >> 3);
            if (rg > T_TOK - 1) rg = T_TOK - 1;
            a_st[t] = *(const f32x4*)(x + (size_t)rg * IN_F + k0 + (c & 7) * 4);
            b_st[t] = *(const f32x4*)(wbase + (size_t)(c >> 3) * IN_F + k0 + (c & 7) * 4);
        }

        __syncthreads();

        #pragma unroll
        for (int t = 0; t < 4; ++t) {
            int c = t * FTHREADS + tid;
            bf16x4 ha, hb;
            #pragma unroll
            for (int j = 0; j < 4; ++j) { ha[j] = (bf16)a_st[t][j]; hb[j] = (bf16)b_st[t][j]; }
            *(bf16x4*)(&Asf[(c >> 3) * FBK + (c & 7) * 4]) = ha;
            *(bf16x4*)(&Bsf[(c >> 3) * FBK + (c & 7) * 4]) = hb;
        }
        __syncthreads();

        bf16x8 af[4], bfr[4];
        #pragma unroll
        for (int t = 0; t < 4; ++t)
            af[t] = *(const bf16x8*)(&Asf[(wm + t * 16 + l16) * FBK + quad * 8]);
        #pragma unroll
        for (int v = 0; v < 4; ++v)
            bfr[v] = *(const bf16x8*)(&Bsf[(wn + v * 16 + l16) * FBK + quad * 8]);

        #pragma unroll
        for (int t = 0; t < 4; ++t)
            #pragma unroll
            for (int v = 0; v < 4; ++v)
                acc[t][v] = __builtin_amdgcn_mfma_f32_16x16x32_bf16(
                    af[t], bfr[v], acc[t][v], 0, 0, 0);
    }

    #pragma unroll
    for (int t = 0; t < 4; ++t) {
        #pragma unroll
        for (int r = 0; r < 4; ++r) {
            int row = wm + t * 16 + quad * 4 + r;
            if (row < rows) {
                size_t ob = (size_t)(row0 + row) * OUT_F + col0;
                #pragma unroll
                for (int v = 0; v < 4; ++v)
                    out[ob + wn + v * 16 + l16] = acc[t][v][r];
            }
        }
    }
}

extern "C" void kernel_launch(void* const* d_in, const int* in_sizes, int n_in,
                              void* d_out, int out_size, void* d_ws, size_t ws_size,
                              hipStream_t stream) {
    const float* x   = (const float*)d_in[0];
    const float* wgt = (const float*)d_in[1];
    const int*   seg = (const int*)d_in[2];
    float* out = (float*)d_out;

    const size_t xbytes = (size_t)T_TOK * IN_F * sizeof(bf16);       // 33.55 MB
    const size_t wbytes = (size_t)NE * OUT_F * IN_F * sizeof(bf16);  // 16.78 MB

    if (ws_size >= xbytes + wbytes) {
        bf16* xb = (bf16*)d_ws;
        bf16* wb = (bf16*)((char*)d_ws + xbytes);
        cvt_and_zero<<<dim3(2048, 1, 1), dim3(CVT_THREADS, 1, 1), 0, stream>>>(
            x, wgt, xb, wb, seg, out);
        grouped_gemm_main<<<dim3(NBLOCKS, 1, 1), dim3(GTHREADS, 1, 1), 0, stream>>>(
            xb, wb, seg, out);
        grouped_gemm_surplus<<<dim3(SP_BLOCKS, 1, 1), dim3(GTHREADS, 1, 1), 0, stream>>>(
            xb, wb, seg, out);
    } else {
        grouped_gemm_f32io_bf16<<<dim3(OUT_F / FBM, FROW_SLOTS, 1),
                                  dim3(FTHREADS, 1, 1), 0, stream>>>(x, wgt, seg, out);
    }
}

// Round 8
// 205.471 us; speedup vs baseline: 1.1526x; 1.0463x over previous
//
#include <hip/hip_runtime.h>

#define T_TOK  16384
#define IN_F   1024
#define OUT_F  1024
#define NE     8

typedef __bf16 bf16;
typedef bf16  bf16x4 __attribute__((ext_vector_type(4)));
typedef bf16  bf16x8 __attribute__((ext_vector_type(8)));
typedef float f32x4  __attribute__((ext_vector_type(4)));

// ---------------------------------------------------------------------------
// Shared GEMM geometry. 256x256 tile, BK=64, 8 waves (2M x 4N).
// ---------------------------------------------------------------------------
#define BM 256
#define BN 256
#define BK 64
#define GTHREADS 512
#define NBLOCKS 256
#define KCH (IN_F / BK)      // 16 K-chunks per tile
#define SP_BLOCKS 112        // 28 surplus tiles x 4 K-slices (max)

// ---------------------------------------------------------------------------
// Pass 1: fp32 -> bf16 convert (bf16x8 = 16B writes) + zero-fill ONLY the
// surplus rows [R64, T_TOK).
// ---------------------------------------------------------------------------
#define CVT_THREADS 256
#define NX8 (T_TOK * IN_F / 8)
#define NW8 (NE * OUT_F * IN_F / 8)
#define NCVT8 (NX8 + NW8)

__global__ __launch_bounds__(CVT_THREADS)
void cvt_and_zero(const float* __restrict__ x, const float* __restrict__ w,
                  bf16* __restrict__ xb, bf16* __restrict__ wb,
                  const int* __restrict__ seg_lens, float* __restrict__ out)
{
    // R64 = first row of slot 64 (slots tile [0,T_TOK) contiguously in order)
    int r64 = T_TOK;
    {
        int slots = 0, start = 0;
        #pragma unroll
        for (int e = 0; e < NE; ++e) {
            int len = seg_lens[e];
            int nt  = (len + BM - 1) >> 8;
            if (slots <= 64 && slots + nt > 64) {
                r64 = start + (64 - slots) * BM;
            }
            slots += nt;
            start += len;
        }
    }
    const int zero8 = (T_TOK - r64) * (OUT_F / 8);
    const int zb8   = r64 * (OUT_F / 8);
    const int tot   = NCVT8 + zero8;

    for (int i = blockIdx.x * CVT_THREADS + threadIdx.x; i < tot;
         i += gridDim.x * CVT_THREADS) {
        if (i < NCVT8) {
            const bool isx = (i < NX8);
            const int  j   = isx ? i : i - NX8;
            f32x4 v0 = isx ? ((const f32x4*)x)[2*j]   : ((const f32x4*)w)[2*j];
            f32x4 v1 = isx ? ((const f32x4*)x)[2*j+1] : ((const f32x4*)w)[2*j+1];
            bf16x8 h;
            #pragma unroll
            for (int k = 0; k < 4; ++k) { h[k] = (bf16)v0[k]; h[4+k] = (bf16)v1[k]; }
            if (isx) ((bf16x8*)xb)[j] = h;
            else     ((bf16x8*)wb)[j] = h;
        } else {
            f32x4 z = {0.f, 0.f, 0.f, 0.f};
            const int j = zb8 + (i - NCVT8);
            ((f32x4*)out)[2*j]   = z;
            ((f32x4*)out)[2*j+1] = z;
        }
    }
}

// ---------------------------------------------------------------------------
// Common helpers
// ---------------------------------------------------------------------------
__device__ __forceinline__ void gld_lds16(const bf16* g, bf16* l) {
    __builtin_amdgcn_global_load_lds(
        (const __attribute__((address_space(1))) void*)g,
        (__attribute__((address_space(3))) void*)l,
        16, 0, 0);
}

__device__ __forceinline__ void resolve_slot(const int* sl, int slot,
                                             int& e_sel, int& row0, int& rows)
{
    e_sel = -1; row0 = 0; rows = 0;
    int start = 0, acct = 0;
    #pragma unroll
    for (int e = 0; e < NE; ++e) {
        int len = sl[e];
        int nt  = (len + BM - 1) >> 8;
        if (e_sel < 0 && slot >= acct && slot < acct + nt) {
            e_sel = e;
            row0  = start + (slot - acct) * BM;
            int rm = start + len - row0;
            rows = rm < BM ? rm : BM;
        }
        acct  += nt;
        start += len;
    }
}

// One full K=64 compute step on buffers Ab/Bb with swizzled reads.
// LDS[row][c] holds global element [row][c ^ 8*(row&7)] (see staging source).
__device__ __forceinline__ void mfma_step(const bf16* __restrict__ Ab,
                                          const bf16* __restrict__ Bb,
                                          f32x4 (&acc)[8][4],
                                          int wr, int wc, int l16, int quad,
                                          int swz8)
{
    #pragma unroll
    for (int kk = 0; kk < 2; ++kk) {
        const int ce = (kk * 32 + quad * 8) ^ swz8;   // swizzled col (elements)
        bf16x8 af[8], bfr[4];
        #pragma unroll
        for (int t = 0; t < 8; ++t)
            af[t] = *(const bf16x8*)(Ab + (wr * 128 + t * 16 + l16) * BK + ce);
        #pragma unroll
        for (int v = 0; v < 4; ++v)
            bfr[v] = *(const bf16x8*)(Bb + (wc * 64 + v * 16 + l16) * BK + ce);
        #pragma unroll
        for (int t = 0; t < 8; ++t)
            #pragma unroll
            for (int v = 0; v < 4; ++v)
                acc[t][v] = __builtin_amdgcn_mfma_f32_16x16x32_bf16(
                    af[t], bfr[v], acc[t][v], 0, 0, 0);
    }
}

// ---------------------------------------------------------------------------
// Pass 2: MAIN kernel — counted-vmcnt pipeline (T4) + read-side XOR swizzle
// (T2, G4 form). Per step: issue next stages, s_waitcnt vmcnt(8) (waits only
// for the PREVIOUS step's 8 loads -> full step of latency cover), raw
// s_barrier, compute, raw s_barrier. No vmcnt(0) drain in the loop.
// Swizzle: linear LDS dest (global_load_lds requirement) + inverse-swizzled
// GLOBAL source + swizzled ds_read (rule #21; involution col ^= 8*(row&7)).
// ---------------------------------------------------------------------------
__global__ __launch_bounds__(GTHREADS)
void grouped_gemm_main(const bf16* __restrict__ xb,
                       const bf16* __restrict__ wb,
                       const int*  __restrict__ seg_lens,
                       float* __restrict__ out)
{
    __shared__ __align__(16) bf16 As[2][BM * BK];   // 2 x 32 KiB
    __shared__ __align__(16) bf16 Bs[2][BN * BK];   // 2 x 32 KiB

    const int tile = blockIdx.x;        // 0..255; L >= 256 always
    const int slot = tile >> 2;
    const int col0 = (tile & 3) << 8;

    int sl[NE];
    #pragma unroll
    for (int e = 0; e < NE; ++e) sl[e] = seg_lens[e];

    int e_sel, row0, rows;
    resolve_slot(sl, slot, e_sel, row0, rows);
    if (e_sel < 0) return;   // unreachable (L >= 256), uniform safety exit

    const int tid  = threadIdx.x;
    const int lane = tid & 63;
    const int wave = tid >> 6;
    const int wr   = wave >> 2;
    const int wc   = wave & 3;
    const int quad = lane >> 4;
    const int l16  = lane & 15;
    const int rq   = lane >> 3;          // row within 8-row staging group
    const int q0   = wave * 4;
    const int swz8 = (l16 & 7) * 8;      // read-side swizzle (elements)

    // staging source column: inverse-swizzled so linear LDS dest ends up
    // holding the swizzled layout. row&7 == rq, col slot (lane&7).
    const int ke_s = (((lane & 7) ^ rq) * 8);

    const bf16* wbase = wb + ((size_t)e_sel * OUT_F + (size_t)col0) * IN_F;

    const bf16* ga[4];
    const bf16* gb[4];
    #pragma unroll
    for (int i = 0; i < 4; ++i) {
        int q  = wave * 4 + i;
        int ra = row0 + q * 8 + rq;
        if (ra > T_TOK - 1) ra = T_TOK - 1;
        ga[i] = xb + (size_t)ra * IN_F + ke_s;
        gb[i] = wbase + (size_t)(q * 8 + rq) * IN_F + ke_s;
    }

    f32x4 acc[8][4] = {};

    // prologue: stage K-chunk 0 into buffer 0 (8 loads in flight)
    #pragma unroll
    for (int i = 0; i < 4; ++i) {
        gld_lds16(ga[i], &As[0][(q0 + i) * 512]);
        gld_lds16(gb[i], &Bs[0][(q0 + i) * 512]);
    }

    for (int n = 0; n < KCH - 1; ++n) {
        // issue next chunk's stages into the alternate buffer (8 loads)
        const int kn  = (n + 1) * BK;
        const int nxt = (n + 1) & 1;
        #pragma unroll
        for (int i = 0; i < 4; ++i) {
            gld_lds16(ga[i] + kn, &As[nxt][(q0 + i) * 512]);
            gld_lds16(gb[i] + kn, &Bs[nxt][(q0 + i) * 512]);
        }
        // wait only for the OLDEST 8 (chunk n's loads, issued last step);
        // the 8 just issued stay in flight across both barriers + compute.
        asm volatile("s_waitcnt vmcnt(8)" ::: "memory");
        __builtin_amdgcn_s_barrier();          // all waves' chunk-n data in LDS
        __builtin_amdgcn_sched_barrier(0);
        mfma_step(&As[n & 1][0], &Bs[n & 1][0], acc, wr, wc, l16, quad, swz8);
        __builtin_amdgcn_sched_barrier(0);
        __builtin_amdgcn_s_barrier();          // all reads of buf[n&1] done
    }
    // epilogue step: last chunk (KCH-1, buffer 1) — drain remaining loads
    asm volatile("s_waitcnt vmcnt(0)" ::: "memory");
    __builtin_amdgcn_s_barrier();
    __builtin_amdgcn_sched_barrier(0);
    mfma_step(&As[(KCH - 1) & 1][0], &Bs[(KCH - 1) & 1][0], acc,
              wr, wc, l16, quad, swz8);

    // epilogue: C/D layout col=lane&15, row=quad*4+reg; plain store
    #pragma unroll
    for (int t = 0; t < 8; ++t) {
        #pragma unroll
        for (int r = 0; r < 4; ++r) {
            int row = wr * 128 + t * 16 + quad * 4 + r;
            if (row < rows) {
                size_t ob = (size_t)(row0 + row) * OUT_F + col0 + wc * 64;
                #pragma unroll
                for (int v = 0; v < 4; ++v)
                    out[ob + v * 16 + l16] = acc[t][v][r];
            }
        }
    }
}

// ---------------------------------------------------------------------------
// Pass 3: SURPLUS kernel — UNCHANGED from r7 (K-split-by-4, single atomic
// flush per block onto pre-zeroed surplus rows). Linear LDS layout.
// ---------------------------------------------------------------------------
__global__ __launch_bounds__(GTHREADS)
void grouped_gemm_surplus(const bf16* __restrict__ xb,
                          const bf16* __restrict__ wb,
                          const int*  __restrict__ seg_lens,
                          float* __restrict__ out)
{
    __shared__ __align__(16) bf16 As[2][BM * BK];
    __shared__ __align__(16) bf16 Bs[2][BN * BK];

    const int tile   = NBLOCKS + (blockIdx.x >> 2);
    const int kslice = blockIdx.x & 3;

    int sl[NE];
    #pragma unroll
    for (int e = 0; e < NE; ++e) sl[e] = seg_lens[e];

    int n_slots = 0;
    #pragma unroll
    for (int e = 0; e < NE; ++e) n_slots += (sl[e] + BM - 1) >> 8;
    const int L = n_slots * (OUT_F / BN);
    if (tile >= L) return;    // block-uniform exit before any barrier

    const int slot = tile >> 2;
    const int col0 = (tile & 3) << 8;
    int e_sel, row0, rows;
    resolve_slot(sl, slot, e_sel, row0, rows);

    const int tid  = threadIdx.x;
    const int lane = tid & 63;
    const int wave = tid >> 6;
    const int wr   = wave >> 2;
    const int wc   = wave & 3;
    const int quad = lane >> 4;
    const int l16  = lane & 15;
    const int rq   = lane >> 3;
    const int ke   = (lane & 7) * 8;
    const int q0   = wave * 4;

    const bf16* wbase = wb + ((size_t)e_sel * OUT_F + (size_t)col0) * IN_F;

    const bf16* ga[4];
    const bf16* gb[4];
    #pragma unroll
    for (int i = 0; i < 4; ++i) {
        int q  = wave * 4 + i;
        int ra = row0 + q * 8 + rq;
        if (ra > T_TOK - 1) ra = T_TOK - 1;
        ga[i] = xb + (size_t)ra * IN_F + ke;
        gb[i] = wbase + (size_t)(q * 8 + rq) * IN_F + ke;
    }

    f32x4 acc[8][4] = {};

    const int kb0 = kslice * 4 * BK;

    #pragma unroll
    for (int i = 0; i < 4; ++i) {
        gld_lds16(ga[i] + kb0, &As[0][(q0 + i) * 512]);
        gld_lds16(gb[i] + kb0, &Bs[0][(q0 + i) * 512]);
    }
    __syncthreads();

    #pragma unroll
    for (int j = 0; j < 4; ++j) {       // static trip count: cur = j&1 static
        const int cur = j & 1;
        if (j < 3) {
            const int kn = kb0 + (j + 1) * BK;
            #pragma unroll
            for (int i = 0; i < 4; ++i) {
                gld_lds16(ga[i] + kn, &As[cur ^ 1][(q0 + i) * 512]);
                gld_lds16(gb[i] + kn, &Bs[cur ^ 1][(q0 + i) * 512]);
            }
        }

        #pragma unroll
        for (int kk = 0; kk < 2; ++kk) {
            bf16x8 af[8], bfr[4];
            #pragma unroll
            for (int t = 0; t < 8; ++t)
                af[t] = *(const bf16x8*)(
                    &As[cur][(wr * 128 + t * 16 + l16) * BK + kk * 32 + quad * 8]);
            #pragma unroll
            for (int v = 0; v < 4; ++v)
                bfr[v] = *(const bf16x8*)(
                    &Bs[cur][(wc * 64 + v * 16 + l16) * BK + kk * 32 + quad * 8]);
            #pragma unroll
            for (int t = 0; t < 8; ++t)
                #pragma unroll
                for (int v = 0; v < 4; ++v)
                    acc[t][v] = __builtin_amdgcn_mfma_f32_16x16x32_bf16(
                        af[t], bfr[v], acc[t][v], 0, 0, 0);
        }

        __syncthreads();
    }

    // single atomic flush (out pre-zeroed over surplus rows)
    #pragma unroll
    for (int t = 0; t < 8; ++t) {
        #pragma unroll
        for (int r = 0; r < 4; ++r) {
            int row = wr * 128 + t * 16 + quad * 4 + r;
            if (row < rows) {
                size_t ob = (size_t)(row0 + row) * OUT_F + col0 + wc * 64;
                #pragma unroll
                for (int v = 0; v < 4; ++v)
                    unsafeAtomicAdd(&out[ob + v * 16 + l16], acc[t][v][r]);
            }
        }
    }
}

// ---------------------------------------------------------------------------
// Fallback (ws too small): round-0 kernel — fp32 loads, in-loop cvt.
// ---------------------------------------------------------------------------
#define FBM 128
#define FBK 32
#define FTHREADS 256
#define FROW_SLOTS 136

__global__ __launch_bounds__(FTHREADS)
void grouped_gemm_f32io_bf16(const float* __restrict__ x,
                             const float* __restrict__ wgt,
                             const int*  __restrict__ seg_lens,
                             float* __restrict__ out)
{
    __shared__ __align__(16) bf16 Asf[FBM * FBK];
    __shared__ __align__(16) bf16 Bsf[FBM * FBK];

    const int m    = blockIdx.y;
    const int col0 = blockIdx.x * FBM;

    int e_sel = -1, row0 = 0, rows = 0;
    {
        int start = 0, acct = 0;
        #pragma unroll
        for (int e = 0; e < NE; ++e) {
            int len = seg_lens[e];
            int nt  = (len + FBM - 1) >> 7;
            if (e_sel < 0 && m >= acct && m < acct + nt) {
                e_sel = e;
                row0  = start + (m - acct) * FBM;
                int rem = start + len - row0;
                rows = rem < FBM ? rem : FBM;
            }
            acct  += nt;
            start += len;
        }
    }
    if (e_sel < 0) return;

    const int tid  = threadIdx.x;
    const int lane = tid & 63;
    const int wave = tid >> 6;
    const int wm   = (wave >> 1) * 64;
    const int wn   = (wave & 1) * 64;
    const int quad = lane >> 4;
    const int l16  = lane & 15;

    const float* wbase = wgt + ((size_t)e_sel * OUT_F + (size_t)col0) * IN_F;

    f32x4 acc[4][4] = {};

    for (int k0 = 0; k0 < IN_F; k0 += FBK) {
        f32x4 a_st[4], b_st[4];
        #pragma unroll
        for (int t = 0; t < 4; ++t) {
            int c  = t * FTHREADS + tid;
            int rg = row0 + (c >> 3);
            if (rg > T_TOK - 1) rg = T_TOK - 1;
            a_st[t] = *(const f32x4*)(x + (size_t)rg * IN_F + k0 + (c & 7) * 4);
            b_st[t] = *(const f32x4*)(wbase + (size_t)(c >> 3) * IN_F + k0 + (c & 7) * 4);
        }

        __syncthreads();

        #pragma unroll
        for (int t = 0; t < 4; ++t) {
            int c = t * FTHREADS + tid;
            bf16x4 ha, hb;
            #pragma unroll
            for (int j = 0; j < 4; ++j) { ha[j] = (bf16)a_st[t][j]; hb[j] = (bf16)b_st[t][j]; }
            *(bf16x4*)(&Asf[(c >> 3) * FBK + (c & 7) * 4]) = ha;
            *(bf16x4*)(&Bsf[(c >> 3) * FBK + (c & 7) * 4]) = hb;
        }
        __syncthreads();

        bf16x8 af[4], bfr[4];
        #pragma unroll
        for (int t = 0; t < 4; ++t)
            af[t] = *(const bf16x8*)(&Asf[(wm + t * 16 + l16) * FBK + quad * 8]);
        #pragma unroll
        for (int v = 0; v < 4; ++v)
            bfr[v] = *(const bf16x8*)(&Bsf[(wn + v * 16 + l16) * FBK + quad * 8]);

        #pragma unroll
        for (int t = 0; t < 4; ++t)
            #pragma unroll
            for (int v = 0; v < 4; ++v)
                acc[t][v] = __builtin_amdgcn_mfma_f32_16x16x32_bf16(
                    af[t], bfr[v], acc[t][v], 0, 0, 0);
    }

    #pragma unroll
    for (int t = 0; t < 4; ++t) {
        #pragma unroll
        for (int r = 0; r < 4; ++r) {
            int row = wm + t * 16 + quad * 4 + r;
            if (row < rows) {
                size_t ob = (size_t)(row0 + row) * OUT_F + col0;
                #pragma unroll
                for (int v = 0; v < 4; ++v)
                    out[ob + wn + v * 16 + l16] = acc[t][v][r];
            }
        }
    }
}

extern "C" void kernel_launch(void* const* d_in, const int* in_sizes, int n_in,
                              void* d_out, int out_size, void* d_ws, size_t ws_size,
                              hipStream_t stream) {
    const float* x   = (const float*)d_in[0];
    const float* wgt = (const float*)d_in[1];
    const int*   seg = (const int*)d_in[2];
    float* out = (float*)d_out;

    const size_t xbytes = (size_t)T_TOK * IN_F * sizeof(bf16);       // 33.55 MB
    const size_t wbytes = (size_t)NE * OUT_F * IN_F * sizeof(bf16);  // 16.78 MB

    if (ws_size >= xbytes + wbytes) {
        bf16* xb = (bf16*)d_ws;
        bf16* wb = (bf16*)((char*)d_ws + xbytes);
        cvt_and_zero<<<dim3(2048, 1, 1), dim3(CVT_THREADS, 1, 1), 0, stream>>>(
            x, wgt, xb, wb, seg, out);
        grouped_gemm_main<<<dim3(NBLOCKS, 1, 1), dim3(GTHREADS, 1, 1), 0, stream>>>(
            xb, wb, seg, out);
        grouped_gemm_surplus<<<dim3(SP_BLOCKS, 1, 1), dim3(GTHREADS, 1, 1), 0, stream>>>(
            xb, wb, seg, out);
    } else {
        grouped_gemm_f32io_bf16<<<dim3(OUT_F / FBM, FROW_SLOTS, 1),
                                  dim3(FTHREADS, 1, 1), 0, stream>>>(x, wgt, seg, out);
    }
}